// Round 4
// baseline (194.334 us; speedup 1.0000x reference)
//
#include <hip/hip_runtime.h>
#include <stdint.h>

// ---- JAX PRNG path: jax_threefry_partitionable (modern default), validated absmax==0
#define SNUM 10
#define NBATCH 4
#define NCLS 4
#define HH 512
#define WW 512
#define IMG (HH*WW)                   // 262144
#define NPIX (SNUM*NBATCH*IMG)        // 10485760
#define WPI (IMG/32)                  // 8192 32-bit words per 512x512 image
#define QCAP 3584                     // BFS fallback queue entries

// ws layout: acc@0 | gkey@64 (120 u32) | misc@1536 | packed@4096 (2.62 MB)
// misc: [0]=filldone [8..127]=arrive[120]

// JAX uniform(minval=tiny, maxval=1): f01 in [0,1) has min positive 2^-23,
// so f01 + tiny == f01 for f01 > 0, and == tiny for f01 == 0  ->  fmaxf.
__device__ __forceinline__ float u01(uint32_t bits) {
  const float f = __uint_as_float((bits >> 9) | 0x3f800000u) - 1.0f;
  return fmaxf(f, 1.17549435e-38f);
}

// unpack: 64-bit packed 2-bit classes XORed with k-pattern -> mask of fields==k
__device__ __forceinline__ uint32_t unpack32(uint64_t v) {
  uint64_t tt = v | (v >> 1);
  uint64_t u = ~tt & 0x5555555555555555ULL;
  u = (u ^ (u >> 1))  & 0x3333333333333333ULL;
  u = (u ^ (u >> 2))  & 0x0F0F0F0F0F0F0F0FULL;
  u = (u ^ (u >> 4))  & 0x00FF00FF00FF00FFULL;
  u = (u ^ (u >> 8))  & 0x0000FFFF0000FFFFULL;
  u = (u ^ (u >> 16)) & 0x00000000FFFFFFFFULL;
  return (uint32_t)u;
}

// ---------------- Kernel A: categorical sampling (validated R6-R8 arithmetic) ----------------
// At its realistic issue roofline: ~1335 VALU inst/thread x 40960 waves at
// ~1.57 GHz sustained (m07: 103/157 TF) = 68 us floor; measured 88 at 86% busy.
// 41.9M threefry hashes are bit-exactness-bound (partitionable: 1 hash/gumbel).
__global__ __launch_bounds__(256) void k_sample(const float* __restrict__ preds,
                                                uint8_t* __restrict__ packed,
                                                float* __restrict__ acc,
                                                uint32_t* __restrict__ gkey,
                                                uint32_t* __restrict__ misc) {
  const int t = blockIdx.x * 256 + threadIdx.x;   // < 2,621,440
  if (t == 0) acc[0] = 0.0f;
  if (t < 120) gkey[t] = 0u;
  if (t >= 120 && t < 256) misc[t - 120] = 0u;    // filldone + arrive[120]
  const int sn = t >> 16;                         // s*4 + n
  const int n  = sn & 3;
  const int pg = t & 65535;
  const int pix = pg << 2;

  float pp[NCLS][4];
#pragma unroll
  for (int c = 0; c < NCLS; ++c) {
    const float4 v = *reinterpret_cast<const float4*>(
        preds + (((int64_t)(n * NCLS + c)) << 18) + pix);
    pp[c][0] = v.x; pp[c][1] = v.y; pp[c][2] = v.z; pp[c][3] = v.w;
  }

  const uint32_t gb = (uint32_t)sn * 1048576u + ((uint32_t)pix << 2);
  const uint32_t k1 = 42u;
  const uint32_t k2 = 42u ^ 0x1BD11BDAu;
  uint32_t byte = 0;

#define TFR4(r) { \
  _Pragma("unroll") \
  for (int c_ = 0; c_ < 4; ++c_) { \
    x0[c_] += x1[c_]; \
    const uint32_t xr_ = x1[c_]; \
    x1[c_] = ((xr_ << (r)) | (xr_ >> (32 - (r)))) ^ x0[c_]; \
  } }
#define INJ4(a, b) { \
  _Pragma("unroll") \
  for (int c_ = 0; c_ < 4; ++c_) { x0[c_] += (a); x1[c_] += (b); } }

#pragma unroll
  for (int j = 0; j < 4; ++j) {
    uint32_t x0[4], x1[4];
#pragma unroll
    for (int c = 0; c < 4; ++c) {
      x0[c] = 0u;                                   // k0 = 0
      x1[c] = gb + (uint32_t)(4 * j + c) + k1;      // counter + k1
    }
    TFR4(13) TFR4(15) TFR4(26) TFR4(6)
    INJ4(k1, k2 + 1u)
    TFR4(17) TFR4(29) TFR4(16) TFR4(24)
    INJ4(k2, 2u)                                    // x1 += k0 + 2
    TFR4(13) TFR4(15) TFR4(26) TFR4(6)
    INJ4(0u, k1 + 3u)                               // x0 += k0 (no-op)
    TFR4(17) TFR4(29) TFR4(16) TFR4(24)
    INJ4(k1, k2 + 4u)
    TFR4(13) TFR4(15) TFR4(26) TFR4(6)
    // final injection fused into output: bits = (x0+k2) ^ (x1+k0+5)
    float lg[4];
#pragma unroll
    for (int c = 0; c < 4; ++c)
      lg[c] = __log2f(u01((x0[c] + k2) ^ (x1[c] + 5u)));   // <= 0

    float bp = pp[0][j];
    float bl = lg[0];
    int bc = 0;
#pragma unroll
    for (int c = 1; c < NCLS; ++c) {
      if (pp[c][j] * bl < bp * lg[c]) { bp = pp[c][j]; bl = lg[c]; bc = c; }
    }
    byte |= (uint32_t)bc << (2 * j);
  }
#undef TFR4
#undef INJ4
  packed[t] = (uint8_t)byte;
}

// ---- BFS fallback helpers (validated R2, LDS-resident, plain queue stores) ----

__device__ __forceinline__ uint32_t runmask(uint32_t m, uint32_t s) {
  uint32_t out = 0;
  while (s) {
    const int j = __ffs(s) - 1;
    const uint32_t bj = 1u << j;
    const uint32_t up = ((m + bj) ^ m) & m;
    const uint32_t rm = __brev(m);
    const uint32_t rbj = 1u << (31 - j);
    const uint32_t dn = __brev(((rm + rbj) ^ rm) & rm);
    const uint32_t run = up | dn;
    out |= run;
    s &= ~run;
  }
  return out;
}

__device__ __forceinline__ void claimf(uint32_t* fg, uint32_t* qw, uint32_t* qb,
                                       uint32_t* qtail, uint32_t t, uint32_t want) {
  const uint32_t old = atomicAnd(&fg[t], ~want);
  uint32_t nb = old & want;
  if (!nb) return;
  const uint32_t ext = runmask(old, nb) & ~nb;
  if (ext) {
    const uint32_t old2 = atomicAnd(&fg[t], ~ext);
    nb |= old2 & ext;
  }
  const uint32_t slot = atomicAdd(qtail, 1u);
  if (slot < QCAP) { qw[slot] = t; qb[slot] = nb; }
}

__device__ __forceinline__ uint64_t shup64(uint64_t v) {
  const uint32_t lo = __shfl_up((unsigned int)v, 1, 64);
  const uint32_t hi = __shfl_up((unsigned int)(v >> 32), 1, 64);
  return ((uint64_t)hi << 32) | lo;
}
__device__ __forceinline__ uint64_t shdn64(uint64_t v) {
  const uint32_t lo = __shfl_down((unsigned int)v, 1, 64);
  const uint32_t hi = __shfl_down((unsigned int)(v >> 32), 1, 64);
  return ((uint64_t)hi << 32) | lo;
}

// ---------------- Kernel B: fused argmax + flood fill (wait-free last-arriver) ----
// 1920 blocks = 120 probs x 16 slabs. Each block: 5x5 neighbor-count argmax for
// its slab -> atomicMax(gkey) -> threadfence -> per-prob arrival counter. The
// 16th arriver runs that prob's fill inline. Fallback BFS is back in PER-BLOCK
// LDS (R3's global+ticket-lock serialization was the regression: escapes are
// not rare, and serialized global claim chains cost ~10x LDS). sfg aliases the
// front of the fallback fg buffer (phase A strictly precedes phase B within a
// block). LDS 61.5 KB -> 2 blocks/CU; argmax phase pays ~4 residency rounds.
__global__ __launch_bounds__(256) void k_af(const float* __restrict__ preds,
                                            const uint8_t* __restrict__ packed,
                                            uint32_t* __restrict__ gkey,
                                            uint32_t* __restrict__ misc,
                                            float* __restrict__ acc,
                                            float* __restrict__ out) {
  __shared__ uint32_t lds[WPI + 2 * QCAP];   // fg | qw | qb  (sfg aliases lds[0:576))
  __shared__ uint32_t qtail;
  __shared__ uint32_t skey;
  __shared__ uint32_t sfin;
  __shared__ uint32_t sbk;
  __shared__ uint32_t sfb;
  __shared__ uint32_t stail;
  __shared__ float    sred[4];
  const int tid = threadIdx.x;
  const int b = blockIdx.x;
  const int prob = b >> 4;
  const int slab = b & 15;
  const int sn = prob % 40;
  const int k  = 1 + prob / 40;
  const int n  = sn & 3;
  if (tid == 0) skey = 0u;

  const uint64_t* p64 = reinterpret_cast<const uint64_t*>(packed);
  const uint64_t pat = (uint64_t)k * 0x5555555555555555ULL;
  uint32_t* sfg = lds;                // phase-A slab buffer (576 words)

  // ---- phase A: 5x5 neighbor-count argmax over this slab (validated) ----
  const int gr0 = slab * 32 - 2;      // first loaded row (may be <0)
  for (int wi = tid; wi < 36 * 16; wi += 256) {
    const int gr = gr0 + (wi >> 4);
    uint32_t m = 0;
    if (gr >= 0 && gr < HH)
      m = unpack32(p64[(int64_t)sn * WPI + (gr << 4) + (wi & 15)] ^ pat);
    sfg[wi] = m;
  }
  __syncthreads();

  uint32_t lbest = 0;
  for (int idx = tid; idx < 512; idx += 256) {    // 2 words per thread
    const int rl = 2 + (idx >> 4);                // local row in LDS
    const int col = idx & 15;
    const uint32_t cw = sfg[(rl << 4) + col];
    if (!cw) continue;
    uint64_t rb[5];
#pragma unroll
    for (int d = 0; d < 5; ++d) {
      const int base = ((rl + d - 2) << 4) + col;
      const uint32_t le = (col > 0)  ? sfg[base - 1] : 0u;
      const uint32_t cu = sfg[base];
      const uint32_t ri = (col < 15) ? sfg[base + 1] : 0u;
      rb[d] = ((uint64_t)(ri & 7u) << 34) | ((uint64_t)cu << 2) | (uint64_t)(le >> 30);
    }
    const int gr = slab * 32 + (idx >> 4);
    uint32_t bits = cw;
    while (bits) {
      const int j = __ffs(bits) - 1;
      bits &= bits - 1;
      int cnt = 0;
#pragma unroll
      for (int d = 0; d < 5; ++d)
        cnt += __popc((uint32_t)(rb[d] >> j) & 0x1fu);
      const uint32_t fidx = (uint32_t)((gr << 9) + (col << 5) + j);
      const uint32_t key = ((uint32_t)cnt << 18) | (0x3FFFFu - fidx);
      lbest = lbest > key ? lbest : key;
    }
  }
#pragma unroll
  for (int off = 32; off > 0; off >>= 1) {
    const uint32_t o = (uint32_t)__shfl_down((int)lbest, off, 64);
    lbest = lbest > o ? lbest : o;
  }
  if ((tid & 63) == 0 && lbest) atomicMax(&skey, lbest);
  __syncthreads();

  // ---- arrival: publish slab result, last of 16 runs the fill ----
  if (tid == 0) {
    if (skey) atomicMax(&gkey[prob], skey);
    __threadfence();
    const uint32_t a = atomicAdd(&misc[8 + prob], 1u);
    uint32_t f = 0u;
    if (a == 15u) { f = 1u; sbk = atomicAdd(&gkey[prob], 0u); }  // coherent read
    sfin = f;
    sfb = 0u;
  }
  __syncthreads();
  if (!sfin) return;

  // ---- phase B: windowed flood fill + reward log-sum (validated R1/R2 logic) ----
  const uint32_t bkey = sbk;
  const uint32_t seed = 0x3FFFFu - (bkey & 0x3FFFFu);
  const float* chan = preds + (((int64_t)n) * NCLS + k) * (int64_t)IMG;
  float local = 0.0f;

  if ((bkey >> 18) != 0u) {        // uniform across block
    if (tid < 64) {
      const int sr = (int)(seed >> 9), sc = (int)(seed & 511);
      // 64 rows x 64 cols register window around the seed
      int r0 = sr - 31; if (r0 < 0) r0 = 0; if (r0 > HH - 64) r0 = HH - 64;
      int cl = (sc >> 5) - (((sc & 31) < 16) ? 1 : 0);
      if (cl < 0) cl = 0; if (cl > 14) cl = 14;
      const int ar = r0 + tid;                  // this lane's absolute row
      const int64_t pb = (int64_t)sn * WPI + (ar << 4) + cl;
      const uint64_t fgw = ((uint64_t)unpack32(p64[pb + 1] ^ pat) << 32)
                         |            unpack32(p64[pb]     ^ pat);
      const uint64_t rfg = __brevll(fgw);
      uint64_t fill = (ar == sr) ? (1ULL << (sc - (cl << 5))) : 0ULL;

      bool conv = false;
      for (int it = 0; it < 2048; ++it) {
        uint64_t up = shup64(fill); if (tid == 0)  up = 0ULL;
        uint64_t dn = shdn64(fill); if (tid == 63) dn = 0ULL;
        const uint64_t sp = fill | up | dn;
        uint64_t s = fgw & (sp | (sp << 1) | (sp >> 1));   // seeds (include fill)
        uint64_t nf = 0ULL;
        while (s) {                                        // full-run horizontal fill
          const int j = __ffsll((unsigned long long)s) - 1;
          const uint64_t upr = ((fgw + (1ULL << j)) ^ fgw) & fgw;
          const uint64_t dnr = __brevll(((rfg + (1ULL << (63 - j))) ^ rfg) & rfg);
          const uint64_t run = upr | dnr;
          nf |= run;
          s &= ~run;
        }
        const bool ch = (nf != fill);
        fill = nf;
        if (__ballot(ch) == 0ULL) { conv = true; break; }
      }

      bool esc = !conv;
      if (fill) {
        if (tid == 0 && r0 > 0) esc = true;
        if (tid == 63 && r0 + 63 < HH - 1) esc = true;
        if ((fill & 1ULL) && cl > 0) esc = true;
        if ((fill >> 63) && cl < 14) esc = true;
      }

      if (__ballot(esc) == 0ULL) {
        uint64_t bits = fill;
        const float* rowp = chan + (int64_t)ar * WW + (cl << 5);
        while (bits) {
          const int j = __ffsll((unsigned long long)bits) - 1;
          bits &= bits - 1;
          local += logf(rowp[j] + 1e-16f);
        }
      } else if (tid == 0) {
        sfb = 1u;
      }
    }
    __syncthreads();

    if (sfb) {
      // ---- fallback: build full fg in LDS, exact word-level BFS (256 thr) ----
      uint32_t* fgb = lds;                 // overwrites sfg (phase A done)
      uint32_t* qw  = lds + WPI;
      uint32_t* qb  = lds + WPI + QCAP;
      if (tid == 0) qtail = 0u;
      for (int wi = tid; wi < WPI; wi += 256)
        fgb[wi] = unpack32(p64[(int64_t)sn * WPI + wi] ^ pat);
      __syncthreads();
      claimf(fgb, qw, qb, &qtail, seed >> 5, 1u << (seed & 31));
      uint32_t head = 0;
      while (true) {
        __syncthreads();
        if (tid == 0) { uint32_t tl = qtail; stail = tl > QCAP ? QCAP : tl; }
        __syncthreads();
        const uint32_t tail = stail;
        if (head >= tail) break;                 // block-uniform
        for (uint32_t i = head + (uint32_t)tid; i < tail; i += 256) {
          const uint32_t w = qw[i], got = qb[i];
          const int row = (int)(w >> 4), cb = (int)(w & 15);
          const uint32_t spread = got | (got << 1) | (got >> 1);
          const bool lo = (got & 1u) != 0u, hi = (got >> 31) != 0u;
          if (row > 0) {
            claimf(fgb, qw, qb, &qtail, w - 16, spread);
            if (cb > 0 && lo)  claimf(fgb, qw, qb, &qtail, w - 17, 0x80000000u);
            if (cb < 15 && hi) claimf(fgb, qw, qb, &qtail, w - 15, 1u);
          }
          if (row < HH - 1) {
            claimf(fgb, qw, qb, &qtail, w + 16, spread);
            if (cb > 0 && lo)  claimf(fgb, qw, qb, &qtail, w + 15, 0x80000000u);
            if (cb < 15 && hi) claimf(fgb, qw, qb, &qtail, w + 17, 1u);
          }
          if (cb > 0 && lo)  claimf(fgb, qw, qb, &qtail, w - 1, 0x80000000u);
          if (cb < 15 && hi) claimf(fgb, qw, qb, &qtail, w + 1, 1u);
        }
        head = tail;
      }
      const uint32_t tot = stail;
      for (uint32_t i = (uint32_t)tid; i < tot; i += 256) {
        const uint32_t w = qw[i];
        uint32_t bits = qb[i];
        const int row = (int)(w >> 4);
        const int colb = (int)(w & 15) << 5;
        const float* rowp = chan + (int64_t)row * WW;
        while (bits) {
          const int j = __ffs(bits) - 1;
          bits &= bits - 1;
          local += logf(rowp[colb + j] + 1e-16f);
        }
      }
    }
  }

  // epilogue: wave reduce, cross-wave combine; last of the 120 fills writes out[0]
#pragma unroll
  for (int off = 32; off > 0; off >>= 1)
    local += __shfl_down(local, off, 64);
  if ((tid & 63) == 0) sred[tid >> 6] = local;
  __syncthreads();
  if (tid == 0) {
    const float tot = sred[0] + sred[1] + sred[2] + sred[3];
    if (tot != 0.0f) atomicAdd(acc, tot);
    __threadfence();
    const uint32_t old = atomicAdd(&misc[0], 1u);
    if (old == 119u) {
      const float s = atomicAdd(acc, 0.0f);      // coherent read of final sum
      out[0] = -s / 10485760.0f;
    }
  }
}

extern "C" void kernel_launch(void* const* d_in, const int* in_sizes, int n_in,
                              void* d_out, int out_size, void* d_ws, size_t ws_size,
                              hipStream_t stream) {
  const float* preds = (const float*)d_in[0];
  float* out = (float*)d_out;
  char* ws = (char*)d_ws;
  // ws layout: acc@0 | gkey@64 (120 u32) | misc@1536 | packed@4096 (2.62 MB)
  float*    acc    = (float*)ws;
  uint32_t* gkey   = (uint32_t*)(ws + 64);
  uint32_t* misc   = (uint32_t*)(ws + 1536);
  uint8_t*  packed = (uint8_t*)(ws + 4096);

  k_sample<<<10240, 256, 0, stream>>>(preds, packed, acc, gkey, misc);
  k_af<<<1920, 256, 0, stream>>>(preds, packed, gkey, misc, acc, out);
}

// Round 5
// 160.357 us; speedup vs baseline: 1.2119x; 1.2119x over previous
//
#include <hip/hip_runtime.h>
#include <stdint.h>

// ---- JAX PRNG path: jax_threefry_partitionable (modern default), validated absmax==0
#define SNUM 10
#define NBATCH 4
#define NCLS 4
#define HH 512
#define WW 512
#define IMG (HH*WW)                   // 262144
#define NPIX (SNUM*NBATCH*IMG)        // 10485760
#define WPI (IMG/32)                  // 8192 32-bit words per 512x512 image
#define QCAP 3584                     // BFS fallback queue entries

// ws layout: acc@0 | gkey@64 (120 u32) | misc@1536 | packed@4096 (2.62 MB)

// JAX uniform(minval=tiny, maxval=1): f01 in [0,1) has min positive 2^-23,
// so f01 + tiny == f01 for f01 > 0, and == tiny for f01 == 0  ->  fmaxf.
__device__ __forceinline__ float u01(uint32_t bits) {
  const float f = __uint_as_float((bits >> 9) | 0x3f800000u) - 1.0f;
  return fmaxf(f, 1.17549435e-38f);
}

// unpack: 64-bit packed 2-bit classes XORed with k-pattern -> mask of fields==k
__device__ __forceinline__ uint32_t unpack32(uint64_t v) {
  uint64_t tt = v | (v >> 1);
  uint64_t u = ~tt & 0x5555555555555555ULL;
  u = (u ^ (u >> 1))  & 0x3333333333333333ULL;
  u = (u ^ (u >> 2))  & 0x0F0F0F0F0F0F0F0FULL;
  u = (u ^ (u >> 4))  & 0x00FF00FF00FF00FFULL;
  u = (u ^ (u >> 8))  & 0x0000FFFF0000FFFFULL;
  u = (u ^ (u >> 16)) & 0x00000000FFFFFFFFULL;
  return (uint32_t)u;
}

// ---------------- Kernel A: categorical sampling (validated R6-R8 arithmetic) ----------------
// At its realistic issue roofline: ~1335 VALU inst/thread x 40960 waves at
// ~1.57 GHz sustained (m07: 103/157 TF) = 68 us floor; measured 88 at 87% busy.
// 41.9M threefry hashes are bit-exactness-bound (partitionable: 1 hash/gumbel).
// DO NOT TOUCH: three source structures (R0 alignbit, R1 interleave, R2
// launch_bounds) all produced identical 24-VGPR / 88-89 us codegen.
__global__ __launch_bounds__(256) void k_sample(const float* __restrict__ preds,
                                                uint8_t* __restrict__ packed,
                                                float* __restrict__ acc,
                                                uint32_t* __restrict__ gkey,
                                                uint32_t* __restrict__ misc) {
  const int t = blockIdx.x * 256 + threadIdx.x;   // < 2,621,440
  if (t == 0) acc[0] = 0.0f;
  if (t < 120) gkey[t] = 0u;
  if (t == 120) misc[0] = 0u;                     // filldone
  const int sn = t >> 16;                         // s*4 + n
  const int n  = sn & 3;
  const int pg = t & 65535;
  const int pix = pg << 2;

  float pp[NCLS][4];
#pragma unroll
  for (int c = 0; c < NCLS; ++c) {
    const float4 v = *reinterpret_cast<const float4*>(
        preds + (((int64_t)(n * NCLS + c)) << 18) + pix);
    pp[c][0] = v.x; pp[c][1] = v.y; pp[c][2] = v.z; pp[c][3] = v.w;
  }

  const uint32_t gb = (uint32_t)sn * 1048576u + ((uint32_t)pix << 2);
  const uint32_t k1 = 42u;
  const uint32_t k2 = 42u ^ 0x1BD11BDAu;
  uint32_t byte = 0;

#define TFR4(r) { \
  _Pragma("unroll") \
  for (int c_ = 0; c_ < 4; ++c_) { \
    x0[c_] += x1[c_]; \
    const uint32_t xr_ = x1[c_]; \
    x1[c_] = ((xr_ << (r)) | (xr_ >> (32 - (r)))) ^ x0[c_]; \
  } }
#define INJ4(a, b) { \
  _Pragma("unroll") \
  for (int c_ = 0; c_ < 4; ++c_) { x0[c_] += (a); x1[c_] += (b); } }

#pragma unroll
  for (int j = 0; j < 4; ++j) {
    uint32_t x0[4], x1[4];
#pragma unroll
    for (int c = 0; c < 4; ++c) {
      x0[c] = 0u;                                   // k0 = 0
      x1[c] = gb + (uint32_t)(4 * j + c) + k1;      // counter + k1
    }
    TFR4(13) TFR4(15) TFR4(26) TFR4(6)
    INJ4(k1, k2 + 1u)
    TFR4(17) TFR4(29) TFR4(16) TFR4(24)
    INJ4(k2, 2u)                                    // x1 += k0 + 2
    TFR4(13) TFR4(15) TFR4(26) TFR4(6)
    INJ4(0u, k1 + 3u)                               // x0 += k0 (no-op)
    TFR4(17) TFR4(29) TFR4(16) TFR4(24)
    INJ4(k1, k2 + 4u)
    TFR4(13) TFR4(15) TFR4(26) TFR4(6)
    // final injection fused into output: bits = (x0+k2) ^ (x1+k0+5)
    float lg[4];
#pragma unroll
    for (int c = 0; c < 4; ++c)
      lg[c] = __log2f(u01((x0[c] + k2) ^ (x1[c] + 5u)));   // <= 0

    float bp = pp[0][j];
    float bl = lg[0];
    int bc = 0;
#pragma unroll
    for (int c = 1; c < NCLS; ++c) {
      if (pp[c][j] * bl < bp * lg[c]) { bp = pp[c][j]; bl = lg[c]; bc = c; }
    }
    byte |= (uint32_t)bc << (2 * j);
  }
#undef TFR4
#undef INJ4
  packed[t] = (uint8_t)byte;
}

// ---------------- Kernel B1: 5x5 neighbor-count argmax (fence-free) ----------------
// 1920 blocks = 120 probs x 16 row-slabs of 32 rows. LDS slab = 36 rows x 16 words.
__global__ __launch_bounds__(256) void k_argmax(const uint8_t* __restrict__ packed,
                                                uint32_t* __restrict__ gkey) {
  __shared__ uint32_t sfg[36 * 16];   // 2304 B
  __shared__ uint32_t skey;
  const int tid = threadIdx.x;
  const int b = blockIdx.x;
  const int prob = b >> 4;
  const int slab = b & 15;
  const int sn = prob % 40;
  const int k  = 1 + prob / 40;
  if (tid == 0) skey = 0u;

  const uint64_t* p64 = reinterpret_cast<const uint64_t*>(packed);
  const uint64_t pat = (uint64_t)k * 0x5555555555555555ULL;
  const int gr0 = slab * 32 - 2;      // first loaded row (may be <0)
  for (int wi = tid; wi < 36 * 16; wi += 256) {
    const int gr = gr0 + (wi >> 4);
    uint32_t m = 0;
    if (gr >= 0 && gr < HH)
      m = unpack32(p64[(int64_t)sn * WPI + (gr << 4) + (wi & 15)] ^ pat);
    sfg[wi] = m;
  }
  __syncthreads();

  uint32_t lbest = 0;
  for (int idx = tid; idx < 512; idx += 256) {    // 2 words per thread
    const int rl = 2 + (idx >> 4);                // local row in LDS
    const int col = idx & 15;
    const uint32_t cw = sfg[(rl << 4) + col];
    if (!cw) continue;
    uint64_t rb[5];
#pragma unroll
    for (int d = 0; d < 5; ++d) {
      const int base = ((rl + d - 2) << 4) + col;
      const uint32_t le = (col > 0)  ? sfg[base - 1] : 0u;
      const uint32_t cu = sfg[base];
      const uint32_t ri = (col < 15) ? sfg[base + 1] : 0u;
      rb[d] = ((uint64_t)(ri & 7u) << 34) | ((uint64_t)cu << 2) | (uint64_t)(le >> 30);
    }
    const int gr = slab * 32 + (idx >> 4);
    uint32_t bits = cw;
    while (bits) {
      const int j = __ffs(bits) - 1;
      bits &= bits - 1;
      int cnt = 0;
#pragma unroll
      for (int d = 0; d < 5; ++d)
        cnt += __popc((uint32_t)(rb[d] >> j) & 0x1fu);
      const uint32_t fidx = (uint32_t)((gr << 9) + (col << 5) + j);
      const uint32_t key = ((uint32_t)cnt << 18) | (0x3FFFFu - fidx);
      lbest = lbest > key ? lbest : key;
    }
  }
#pragma unroll
  for (int off = 32; off > 0; off >>= 1) {
    const uint32_t o = (uint32_t)__shfl_down((int)lbest, off, 64);
    lbest = lbest > o ? lbest : o;
  }
  if ((threadIdx.x & 63) == 0 && lbest) atomicMax(&skey, lbest);
  __syncthreads();
  if (tid == 0 && skey) atomicMax(&gkey[prob], skey);
}

// ---- flood/BFS helpers (validated) ----

__device__ __forceinline__ uint32_t runmask(uint32_t m, uint32_t s) {
  uint32_t out = 0;
  while (s) {
    const int j = __ffs(s) - 1;
    const uint32_t bj = 1u << j;
    const uint32_t up = ((m + bj) ^ m) & m;
    const uint32_t rm = __brev(m);
    const uint32_t rbj = 1u << (31 - j);
    const uint32_t dn = __brev(((rm + rbj) ^ rm) & rm);
    const uint32_t run = up | dn;
    out |= run;
    s &= ~run;
  }
  return out;
}

// 64-bit run fill: union of contiguous runs of m containing bits of s
__device__ __forceinline__ uint64_t runmask64(uint64_t m, uint64_t s) {
  uint64_t out = 0;
  while (s) {
    const int j = __ffsll((unsigned long long)s) - 1;
    const uint64_t bj = 1ULL << j;
    const uint64_t up = ((m + bj) ^ m) & m;
    const uint64_t rm = __brevll(m);
    const uint64_t rbj = 1ULL << (63 - j);
    const uint64_t dn = __brevll(((rm + rbj) ^ rm) & rm);
    const uint64_t run = up | dn;
    out |= run;
    s &= ~run;
  }
  return out;
}

__device__ __forceinline__ void claimf(uint32_t* fg, uint32_t* qw, uint32_t* qb,
                                       uint32_t* qtail, uint32_t t, uint32_t want) {
  const uint32_t old = atomicAnd(&fg[t], ~want);
  uint32_t nb = old & want;
  if (!nb) return;
  const uint32_t ext = runmask(old, nb) & ~nb;
  if (ext) {
    const uint32_t old2 = atomicAnd(&fg[t], ~ext);
    nb |= old2 & ext;
  }
  const uint32_t slot = atomicAdd(qtail, 1u);
  if (slot < QCAP) { qw[slot] = t; qb[slot] = nb; }
}

__device__ __forceinline__ uint64_t shup64(uint64_t v) {
  const uint32_t lo = __shfl_up((unsigned int)v, 1, 64);
  const uint32_t hi = __shfl_up((unsigned int)(v >> 32), 1, 64);
  return ((uint64_t)hi << 32) | lo;
}
__device__ __forceinline__ uint64_t shdn64(uint64_t v) {
  const uint32_t lo = __shfl_down((unsigned int)v, 1, 64);
  const uint32_t hi = __shfl_down((unsigned int)(v >> 32), 1, 64);
  return ((uint64_t)hi << 32) | lo;
}

// ---------------- Kernel B2: tiered flood fill + reward sum + final ----------------
// 120 blocks x 64 threads (one wave). Tier-1: 64x64 register window (validated).
// Tier-2 (NEW): 128 rows x 512 cols register fill, 2 rows/lane x 8 u64 words —
// full-width, so only components taller than 128 rows escape to tier-3. This
// removes the common escape class (window-border touch) from the ~50 us BFS
// path. Tier-3: validated barrier-free word-level LDS BFS (R0 form).
__global__ __launch_bounds__(64, 1) void k_fill(const float* __restrict__ preds,
                                                const uint8_t* __restrict__ packed,
                                                const uint32_t* __restrict__ gkey,
                                                uint32_t* __restrict__ misc,
                                                float* __restrict__ acc,
                                                float* __restrict__ out) {
  __shared__ uint32_t fg[WPI];     // tier-3 only
  __shared__ uint32_t qw[QCAP];
  __shared__ uint32_t qb[QCAP];
  __shared__ uint32_t qtail;
  const int tid = threadIdx.x;     // 0..63
  const int prob = blockIdx.x;
  const int sn = prob % 40;
  const int k  = 1 + prob / 40;
  const int n  = sn & 3;
  uint32_t* filldone = misc + 0;

  const uint32_t bkey = gkey[prob];
  float local = 0.0f;
  if ((bkey >> 18) != 0u) {
    const uint32_t seed = 0x3FFFFu - (bkey & 0x3FFFFu);
    const int sr = (int)(seed >> 9), sc = (int)(seed & 511);
    const float* chan = preds + (((int64_t)n) * NCLS + k) * (int64_t)IMG;
    const uint64_t* p64 = reinterpret_cast<const uint64_t*>(packed);
    const uint64_t pat = (uint64_t)k * 0x5555555555555555ULL;

    // ---- tier-1: windowed register flood fill, 64 rows x 64 cols (validated) ----
    int r0 = sr - 31; if (r0 < 0) r0 = 0; if (r0 > HH - 64) r0 = HH - 64;
    int cl = (sc >> 5) - (((sc & 31) < 16) ? 1 : 0);
    if (cl < 0) cl = 0; if (cl > 14) cl = 14;
    const int ar = r0 + tid;                  // this lane's absolute row
    const int64_t pb = (int64_t)sn * WPI + (ar << 4) + cl;
    const uint64_t fgw = ((uint64_t)unpack32(p64[pb + 1] ^ pat) << 32)
                       |            unpack32(p64[pb]     ^ pat);
    uint64_t fill = (ar == sr) ? (1ULL << (sc - (cl << 5))) : 0ULL;

    bool conv = false;
    for (int it = 0; it < 256; ++it) {
      uint64_t up = shup64(fill); if (tid == 0)  up = 0ULL;
      uint64_t dn = shdn64(fill); if (tid == 63) dn = 0ULL;
      const uint64_t sp = fill | up | dn;
      const uint64_t s = fgw & (sp | (sp << 1) | (sp >> 1)) & ~fill;
      uint64_t nf = fill;
      if (s) nf |= runmask64(fgw, s);
      const bool ch = (nf != fill);
      fill = nf;
      if (__ballot(ch) == 0ULL) { conv = true; break; }
    }

    bool esc = !conv;
    if (fill) {
      if (tid == 0 && r0 > 0) esc = true;
      if (tid == 63 && r0 + 63 < HH - 1) esc = true;
      if ((fill & 1ULL) && cl > 0) esc = true;
      if ((fill >> 63) && cl < 14) esc = true;
    }

    if (__ballot(esc) == 0ULL) {
      uint64_t bits = fill;
      const float* rowp = chan + (int64_t)ar * WW + (cl << 5);
      while (bits) {
        const int j = __ffsll((unsigned long long)bits) - 1;
        bits &= bits - 1;
        local += logf(rowp[j] + 1e-16f);
      }
    } else {
      // ---- tier-2: 128 rows x 512 cols register fill (2 rows/lane) ----
      bool done2 = false;
      {
        int r0w = sr - 63; if (r0w < 0) r0w = 0; if (r0w > HH - 128) r0w = HH - 128;
        const int row0 = r0w + 2 * tid;            // lane's rows: row0, row0+1
        uint64_t fg2[2][8], fl2[2][8];
#pragma unroll
        for (int rp = 0; rp < 2; ++rp) {
          const int64_t base = (int64_t)sn * WPI + ((int64_t)(row0 + rp) << 4);
#pragma unroll
          for (int w = 0; w < 8; ++w)
            fg2[rp][w] = ((uint64_t)unpack32(p64[base + 2 * w + 1] ^ pat) << 32)
                       |            unpack32(p64[base + 2 * w    ] ^ pat);
        }
        const int srp = (sr - r0w) & 1;
        const int sln = (sr - r0w) >> 1;
#pragma unroll
        for (int rp = 0; rp < 2; ++rp)
#pragma unroll
          for (int w = 0; w < 8; ++w)
            fl2[rp][w] = (tid == sln && rp == srp && w == (sc >> 6))
                         ? (1ULL << (sc & 63)) : 0ULL;

        bool conv2 = false;
        for (int it = 0; it < 192; ++it) {
          bool ch = false;
          uint64_t sp0[8], sp1[8];
#pragma unroll
          for (int w = 0; w < 8; ++w) {
            uint64_t up = shup64(fl2[1][w]); if (tid == 0)  up = 0ULL;
            uint64_t dn = shdn64(fl2[0][w]); if (tid == 63) dn = 0ULL;
            sp0[w] = fl2[0][w] | up        | fl2[1][w];
            sp1[w] = fl2[1][w] | fl2[0][w] | dn;
          }
#pragma unroll
          for (int rp = 0; rp < 2; ++rp) {
            uint64_t nf[8];
#pragma unroll
            for (int w = 0; w < 8; ++w) {
              const uint64_t spw = rp ? sp1[w] : sp0[w];
              uint64_t spread = spw | (spw << 1) | (spw >> 1);
              if (w > 0) spread |= ((rp ? sp1[w-1] : sp0[w-1]) >> 63);
              if (w < 7) spread |= ((rp ? sp1[w+1] : sp0[w+1]) & 1ULL) << 63;
              const uint64_t s = spread & fg2[rp][w] & ~fl2[rp][w];
              nf[w] = fl2[rp][w];
              if (s) nf[w] |= runmask64(fg2[rp][w], s);
            }
            // cross-word run stitching: one L->R then one R->L pass
#pragma unroll
            for (int w = 1; w < 8; ++w)
              if ((nf[w-1] >> 63) && (fg2[rp][w] & 1ULL) && !(nf[w] & 1ULL))
                nf[w] |= runmask64(fg2[rp][w], 1ULL);
#pragma unroll
            for (int w = 6; w >= 0; --w)
              if ((nf[w+1] & 1ULL) && (fg2[rp][w] >> 63) && !(nf[w] >> 63))
                nf[w] |= runmask64(fg2[rp][w], 1ULL << 63);
#pragma unroll
            for (int w = 0; w < 8; ++w) {
              ch |= (nf[w] != fl2[rp][w]);
              fl2[rp][w] = nf[w];
            }
          }
          if (__ballot(ch) == 0ULL) { conv2 = true; break; }
        }

        bool esc2 = !conv2;
        {
          bool any0 = false, any1 = false;
#pragma unroll
          for (int w = 0; w < 8; ++w) { any0 |= (fl2[0][w] != 0ULL); any1 |= (fl2[1][w] != 0ULL); }
          if (tid == 0  && r0w > 0            && any0) esc2 = true;
          if (tid == 63 && r0w + 127 < HH - 1 && any1) esc2 = true;
        }
        if (__ballot(esc2) == 0ULL) {
          done2 = true;
#pragma unroll
          for (int rp = 0; rp < 2; ++rp) {
            const float* rowp = chan + (int64_t)(row0 + rp) * WW;
#pragma unroll
            for (int w = 0; w < 8; ++w) {
              uint64_t bits = fl2[rp][w];
              while (bits) {
                const int j = __ffsll((unsigned long long)bits) - 1;
                bits &= bits - 1;
                local += logf(rowp[(w << 6) + j] + 1e-16f);
              }
            }
          }
        }
      }

      if (!done2) {
        // ---- tier-3: full fg in LDS, exact word-level BFS (validated R0 form) ----
        if (tid == 0) qtail = 0u;
        for (int wi = tid; wi < WPI; wi += 64)
          fg[wi] = unpack32(p64[(int64_t)sn * WPI + wi] ^ pat);
        __syncthreads();
        claimf(fg, qw, qb, &qtail, seed >> 5, 1u << (seed & 31));
        uint32_t head = 0;
        while (true) {
          uint32_t tail = atomicAdd(&qtail, 0u);
          if (tail > QCAP) tail = QCAP;
          if (head >= tail) break;
          for (uint32_t i = head + (uint32_t)tid; i < tail; i += 64) {
            const uint32_t w = qw[i], got = qb[i];
            const int row = (int)(w >> 4), cb = (int)(w & 15);
            const uint32_t spread = got | (got << 1) | (got >> 1);
            const bool lo = (got & 1u) != 0u, hi = (got >> 31) != 0u;
            if (row > 0) {
              claimf(fg, qw, qb, &qtail, w - 16, spread);
              if (cb > 0 && lo)  claimf(fg, qw, qb, &qtail, w - 17, 0x80000000u);
              if (cb < 15 && hi) claimf(fg, qw, qb, &qtail, w - 15, 1u);
            }
            if (row < HH - 1) {
              claimf(fg, qw, qb, &qtail, w + 16, spread);
              if (cb > 0 && lo)  claimf(fg, qw, qb, &qtail, w + 15, 0x80000000u);
              if (cb < 15 && hi) claimf(fg, qw, qb, &qtail, w + 17, 1u);
            }
            if (cb > 0 && lo)  claimf(fg, qw, qb, &qtail, w - 1, 0x80000000u);
            if (cb < 15 && hi) claimf(fg, qw, qb, &qtail, w + 1, 1u);
          }
          head = tail;
        }
        uint32_t tot = qtail; if (tot > QCAP) tot = QCAP;
        for (uint32_t i = (uint32_t)tid; i < tot; i += 64) {
          const uint32_t w = qw[i];
          uint32_t bits = qb[i];
          const int row = (int)(w >> 4);
          const int colb = (int)(w & 15) << 5;
          const float* rowp = chan + (int64_t)row * WW;
          while (bits) {
            const int j = __ffs(bits) - 1;
            bits &= bits - 1;
            local += logf(rowp[colb + j] + 1e-16f);
          }
        }
      }
    }
  }

  // epilogue: reduce, accumulate; last of the 120 blocks writes out[0]
#pragma unroll
  for (int off = 32; off > 0; off >>= 1)
    local += __shfl_down(local, off, 64);
  if (tid == 0) {
    if (local != 0.0f) atomicAdd(acc, local);
    __threadfence();
    const uint32_t old = atomicAdd(filldone, 1u);
    if (old == 119u) {
      const float s = atomicAdd(acc, 0.0f);      // coherent read of final sum
      out[0] = -s / 10485760.0f;
    }
  }
}

extern "C" void kernel_launch(void* const* d_in, const int* in_sizes, int n_in,
                              void* d_out, int out_size, void* d_ws, size_t ws_size,
                              hipStream_t stream) {
  const float* preds = (const float*)d_in[0];
  float* out = (float*)d_out;
  char* ws = (char*)d_ws;
  // ws layout: acc@0 | gkey@64 (120 u32) | misc@1536 | packed@4096 (2.62 MB)
  float*    acc    = (float*)ws;
  uint32_t* gkey   = (uint32_t*)(ws + 64);
  uint32_t* misc   = (uint32_t*)(ws + 1536);
  uint8_t*  packed = (uint8_t*)(ws + 4096);

  k_sample<<<10240, 256, 0, stream>>>(preds, packed, acc, gkey, misc);
  k_argmax<<<1920, 256, 0, stream>>>(packed, gkey);
  k_fill<<<120, 64, 0, stream>>>(preds, packed, gkey, misc, acc, out);
}